// Round 6
// baseline (451.137 us; speedup 1.0000x reference)
//
#include <hip/hip_runtime.h>
#include <hip/hip_bf16.h>
#include <math.h>

typedef __hip_bfloat16 bf16;
typedef short bf8_t __attribute__((ext_vector_type(8)));
typedef float f4_t  __attribute__((ext_vector_type(4)));
#define MFMA16(a,b,c) __builtin_amdgcn_mfma_f32_16x16x32_bf16(a,b,c,0,0,0)
#define DEV __device__ __forceinline__

DEV float bf2f(bf16 h){ return __bfloat162float(h); }
DEV bf16 f2bf(float f){ return __float2bfloat16(f); }
DEV float ld(const void* p, size_t i, int md){
  return md ? ((const float*)p)[i] : bf2f(((const bf16*)p)[i]);
}
DEV float wred(float v){
  #pragma unroll
  for(int off=32; off>0; off>>=1) v += __shfl_down(v, off, 64);
  return __shfl(v, 0, 64);
}

// ---------------- K0: detect input dtype
__global__ __launch_bounds__(256) void k_detect(const unsigned short* __restrict__ xr, int* __restrict__ flag){
  __shared__ float sm[256];
  int t = threadIdx.x;
  float m = 0.f;
  for(int i=t;i<8192;i+=256){
    unsigned int w = ((unsigned int)xr[i]) << 16;
    float v = fabsf(__uint_as_float(w));
    if(v != v) v = 1e30f;
    m = fmaxf(m, v);
  }
  sm[t] = m; __syncthreads();
  if(t == 0){
    float mm = 0.f;
    for(int i=0;i<256;i++) mm = fmaxf(mm, sm[i]);
    *flag = (mm > 1e10f) ? 1 : 0;
  }
}

// ---------------- K0b: convert GEMM weights to bf16 workspace copies
__global__ __launch_bounds__(256) void k_wcvt(const void* __restrict__ inw, const void* __restrict__ outw,
                                              const void* __restrict__ projw, const void* __restrict__ pww,
                                              bf16* __restrict__ dst, const int* __restrict__ modep){
  const int md = *modep;
  int g = blockIdx.x*256 + threadIdx.x;
  if(g >= 155648) return;
  const void* src; int i;
  if(g < 16384){ src = inw;   i = g; }
  else if(g < 24576){ src = outw;  i = g - 16384; }
  else if(g < 90112){ src = projw; i = g - 24576; }
  else { src = pww; i = g - 90112; }
  dst[g] = f2bf(ld(src, (size_t)i, md));
}

// ---------------- K1: LayerNorm over C=256 -> xnorm[B,L,256] (bf16)
__global__ __launch_bounds__(256) void k_ln1(const void* __restrict__ x, const void* __restrict__ gam,
                                             const void* __restrict__ bet, bf16* __restrict__ xnb,
                                             const int* __restrict__ modep){
  const int md = *modep;
  int lane = threadIdx.x & 63, wv = threadIdx.x >> 6;
  int row = blockIdx.x*4 + wv;
  int b = row >> 12, l = row & 4095;
  size_t xb = ((size_t)b << 20) + l;
  float v[4], s=0.f, s2=0.f;
  #pragma unroll
  for(int i=0;i<4;i++){
    int c = lane + (i<<6);
    v[i] = ld(x, xb + ((size_t)c << 12), md);
    s += v[i]; s2 += v[i]*v[i];
  }
  s = wred(s); s2 = wred(s2);
  float mu = s*(1.f/256.f);
  float rs = rsqrtf(s2*(1.f/256.f) - mu*mu + 1e-5f);
  bf16* o = xnb + (size_t)row*256;
  #pragma unroll
  for(int i=0;i<4;i++){
    int c = lane + (i<<6);
    o[c] = f2bf((v[i]-mu)*rs*ld(gam,c,md) + ld(bet,c,md));
  }
}

// ---------------- K2: in_proj MFMA  (M=65536 rows, K=64, N=256 -> xc|z)
__global__ __launch_bounds__(256) void k_inproj(const bf16* __restrict__ xnb, const bf16* __restrict__ wb,
                                                bf16* __restrict__ xcb, bf16* __restrict__ zb){
  __shared__ bf16 As[64*72];
  __shared__ bf16 Ws[256*72];
  int t = threadIdx.x;
  int bm = blockIdx.x >> 6, lt = blockIdx.x & 63;
  int p = bm >> 2, b = bm & 3, l0 = lt << 6;
  #pragma unroll
  for(int pass=0; pass<2; pass++){
    int idx = t + pass*256, r = idx >> 3, ch = idx & 7;
    *(uint4*)&As[r*72 + ch*8] = *(const uint4*)&xnb[((size_t)(b*4096 + l0 + r))*256 + p*64 + ch*8];
  }
  #pragma unroll
  for(int pass=0; pass<8; pass++){
    int idx = t + pass*256, e = idx >> 3, ch = idx & 7;
    *(uint4*)&Ws[e*72 + ch*8] = *(const uint4*)&wb[(size_t)e*64 + ch*8];
  }
  __syncthreads();
  int lane = t & 63, w = t >> 6, quad = lane >> 4, lr = lane & 15;
  f4_t acc[16];
  #pragma unroll
  for(int nt=0;nt<16;nt++) acc[nt] = (f4_t){0.f,0.f,0.f,0.f};
  #pragma unroll
  for(int kk=0; kk<64; kk+=32){
    bf8_t a = *(const bf8_t*)&As[(w*16 + lr)*72 + kk + quad*8];
    #pragma unroll
    for(int nt=0;nt<16;nt++){
      bf8_t bb = *(const bf8_t*)&Ws[(nt*16 + lr)*72 + kk + quad*8];
      acc[nt] = MFMA16(a, bb, acc[nt]);
    }
  }
  __syncthreads();
  bf16* Sl = Ws;  // [64 l][264]
  #pragma unroll
  for(int nt=0;nt<16;nt++)
    #pragma unroll
    for(int r=0;r<4;r++)
      Sl[(w*16 + quad*4 + r)*264 + nt*16 + lr] = f2bf(acc[nt][r]);
  __syncthreads();
  #pragma unroll
  for(int pass=0; pass<8; pass++){
    int idx = t + pass*256, l = idx >> 5, c16 = idx & 31;
    int e0 = c16*8;
    uint4 v = *(uint4*)&Sl[l*264 + e0];
    size_t row = (size_t)bm*4096 + l0 + l;
    if(e0 < 128) *(uint4*)&xcb[row*128 + e0] = v;
    else         *(uint4*)&zb[row*128 + e0 - 128] = v;
  }
}

// ---------------- K3: causal depthwise conv1d(4) + bias + SiLU; 4 l per thread
__global__ __launch_bounds__(256) void k_conv(const bf16* __restrict__ xcb, const void* __restrict__ cw,
                                              const void* __restrict__ cb, bf16* __restrict__ xsb,
                                              const int* __restrict__ modep){
  const int md = *modep;
  int g = blockIdx.x*256 + threadIdx.x;    // 16*1024*128
  int d = g & 127;
  int t2 = g >> 7;
  int lq = t2 & 1023;
  int bm = t2 >> 10;
  int l = lq << 2;
  float w0 = ld(cw,(d<<2)+0,md), w1 = ld(cw,(d<<2)+1,md), w2 = ld(cw,(d<<2)+2,md), w3 = ld(cw,(d<<2)+3,md);
  float bias = ld(cb, d, md);
  size_t base = ((size_t)bm*4096 + l)*128 + d;
  float xm3 = (l>=3)? bf2f(xcb[base - 3*128]) : 0.f;
  float xm2 = (l>=2)? bf2f(xcb[base - 2*128]) : 0.f;
  float xm1 = (l>=1)? bf2f(xcb[base - 1*128]) : 0.f;
  float x0 = bf2f(xcb[base]);
  float x1 = bf2f(xcb[base + 128]);
  float x2 = bf2f(xcb[base + 2*128]);
  float x3 = bf2f(xcb[base + 3*128]);
  float o0 = fmaf(xm3,w0, fmaf(xm2,w1, fmaf(xm1,w2, fmaf(x0,w3, bias))));
  float o1 = fmaf(xm2,w0, fmaf(xm1,w1, fmaf(x0 ,w2, fmaf(x1,w3, bias))));
  float o2 = fmaf(xm1,w0, fmaf(x0 ,w1, fmaf(x1 ,w2, fmaf(x2,w3, bias))));
  float o3 = fmaf(x0 ,w0, fmaf(x1 ,w1, fmaf(x2 ,w2, fmaf(x3,w3, bias))));
  xsb[base]         = f2bf(o0 / (1.f + __expf(-o0)));
  xsb[base + 128]   = f2bf(o1 / (1.f + __expf(-o1)));
  xsb[base + 2*128] = f2bf(o2 / (1.f + __expf(-o2)));
  xsb[base + 3*128] = f2bf(o3 / (1.f + __expf(-o3)));
}

// ---------------- K4: x_proj -> xdt f32[rows][4], xbc bf16[rows][32]
__global__ __launch_bounds__(256) void k_xproj(const bf16* __restrict__ xsb, const void* __restrict__ w,
                                               float* __restrict__ xdt, bf16* __restrict__ xbc,
                                               const int* __restrict__ modep){
  __shared__ float At[128*68];
  __shared__ float Ww[128*40];
  const int md = *modep;
  int t = threadIdx.x;
  int bm = blockIdx.x >> 6, lt = blockIdx.x & 63, l0 = lt << 6;
  for(int idx = t; idx < 4608; idx += 256){
    int e = idx >> 7, k = idx & 127;
    Ww[k*40 + e] = ld(w, idx, md);
  }
  for(int idx = t; idx < 8192; idx += 256){
    int l = idx >> 7, k = idx & 127;
    At[k*68 + l] = bf2f(xsb[((size_t)bm*4096 + l0 + l)*128 + k]);
  }
  __syncthreads();
  int l = t & 63, eg = t >> 6;
  float acc[9] = {};
  for(int k=0;k<128;k++){
    float a = At[k*68 + l];
    #pragma unroll
    for(int j=0;j<9;j++) acc[j] = fmaf(a, Ww[k*40 + eg*9 + j], acc[j]);
  }
  size_t row = (size_t)bm*4096 + l0 + l;
  #pragma unroll
  for(int j=0;j<9;j++){
    int e = eg*9 + j;
    if(e < 4) xdt[row*4 + e] = acc[j];
    else      xbc[row*32 + e - 4] = f2bf(acc[j]);
  }
}

// ---------------- K5a: scan phase1 — chunks of 32, prefetched u, bf16 B
__global__ __launch_bounds__(128) void k_scan1(const bf16* __restrict__ xsb, const float* __restrict__ xdt,
                                               const bf16* __restrict__ xbc,
                                               const void* __restrict__ dtw, const void* __restrict__ dtb,
                                               const void* __restrict__ Alog,
                                               float* __restrict__ CP, bf16* __restrict__ CSb,
                                               const int* __restrict__ modep){
  __shared__ float sdt[32*4];
  __shared__ bf16  sB[32*16];
  const int md = *modep;
  int d = threadIdx.x;
  int bm = blockIdx.x >> 7, c = blockIdx.x & 127;
  size_t row0 = (size_t)bm*4096 + (c<<5);
  if(d < 32) *(float4*)&sdt[d*4] = *(const float4*)&xdt[(row0 + d)*4];
  if(d >= 64){
    int i = d - 64;                 // 0..63: row=i>>1, half=i&1
    int r = i >> 1, hh = i & 1;
    *(uint4*)&sB[r*16 + hh*8] = *(const uint4*)&xbc[(row0 + r)*32 + hh*8];
  }
  bf16 upre[32];
  #pragma unroll
  for(int tt=0;tt<32;tt++) upre[tt] = xsb[(row0 + tt)*128 + d];
  float A[16];
  #pragma unroll
  for(int s=0;s<16;s++) A[s] = -expf(ld(Alog, (d<<4)+s, md));
  float wdt[4];
  #pragma unroll
  for(int j=0;j<4;j++) wdt[j] = ld(dtw, (d<<2)+j, md);
  float bdt = ld(dtb, d, md);
  __syncthreads();
  float h[16] = {};
  float sumd = 0.f;
  for(int tt=0;tt<32;tt++){
    float4 dt4 = *(const float4*)&sdt[tt*4];
    float v = fmaf(dt4.x,wdt[0], fmaf(dt4.y,wdt[1], fmaf(dt4.z,wdt[2], fmaf(dt4.w,wdt[3], bdt))));
    float dv = fmaxf(v,0.f) + __logf(1.f + __expf(-fabsf(v)));
    float u = bf2f(upre[tt]);
    float du = dv*u; sumd += dv;
    uint4 b0 = *(const uint4*)&sB[tt*16];
    uint4 b1 = *(const uint4*)&sB[tt*16 + 8];
    const bf16* B8a = (const bf16*)&b0;
    const bf16* B8b = (const bf16*)&b1;
    #pragma unroll
    for(int s=0;s<8;s++) h[s]   = fmaf(h[s],   __expf(dv*A[s]),   du*bf2f(B8a[s]));
    #pragma unroll
    for(int s=0;s<8;s++) h[s+8] = fmaf(h[s+8], __expf(dv*A[s+8]), du*bf2f(B8b[s]));
  }
  size_t ob = ((size_t)(bm*128 + c)*128 + d) << 4;
  #pragma unroll
  for(int s=0;s<16;s++){ CP[ob+s] = __expf(sumd*A[s]); CSb[ob+s] = f2bf(h[s]); }
}

// ---------------- K5b: scan phase2 — batched prefetch, serial combine of 128 chunks
__global__ __launch_bounds__(256) void k_scan2(float* __restrict__ CP, const bf16* __restrict__ CSb){
  int g = blockIdx.x*256 + threadIdx.x;   // 32768
  int bm = g >> 11, ds = g & 2047;
  size_t base = ((size_t)bm*128 << 11) + ds;
  float h = 0.f;
  float P[8], S[8], Pn[8], Sn[8];
  #pragma unroll
  for(int j=0;j<8;j++){ P[j] = CP[base + ((size_t)j<<11)]; S[j] = bf2f(CSb[base + ((size_t)j<<11)]); }
  for(int cb=0; cb<128; cb+=8){
    if(cb + 8 < 128){
      #pragma unroll
      for(int j=0;j<8;j++){
        size_t idx = base + ((size_t)(cb+8+j) << 11);
        Pn[j] = CP[idx]; Sn[j] = bf2f(CSb[idx]);
      }
    }
    #pragma unroll
    for(int j=0;j<8;j++){
      CP[base + ((size_t)(cb+j) << 11)] = h;
      h = fmaf(P[j], h, S[j]);
    }
    #pragma unroll
    for(int j=0;j<8;j++){ P[j] = Pn[j]; S[j] = Sn[j]; }
  }
}

// ---------------- K5c: scan phase3 — prefetched u,z; bf16 B,C; y overwrites z
__global__ __launch_bounds__(128) void k_scan3(bf16* __restrict__ zb, const bf16* __restrict__ xsb,
                                               const float* __restrict__ xdt, const bf16* __restrict__ xbc,
                                               const void* __restrict__ dtw, const void* __restrict__ dtb,
                                               const void* __restrict__ Alog, const void* __restrict__ Dw,
                                               const float* __restrict__ CP, const int* __restrict__ modep){
  __shared__ float sdt[32*4];
  __shared__ bf16  sBC[32*32];
  const int md = *modep;
  int d = threadIdx.x;
  int bm = blockIdx.x >> 7, c = blockIdx.x & 127;
  size_t row0 = (size_t)bm*4096 + (c<<5);
  if(d < 32) *(float4*)&sdt[d*4] = *(const float4*)&xdt[(row0 + d)*4];
  {
    int r = d >> 2, q = d & 3;      // 128 threads: 32 rows x 4 segs of 8 bf16
    *(uint4*)&sBC[r*32 + q*8] = *(const uint4*)&xbc[(row0 + r)*32 + q*8];
  }
  bf16 upre[32], zpre[32];
  #pragma unroll
  for(int tt=0;tt<32;tt++) upre[tt] = xsb[(row0 + tt)*128 + d];
  #pragma unroll
  for(int tt=0;tt<32;tt++) zpre[tt] = zb[(row0 + tt)*128 + d];
  float A[16];
  #pragma unroll
  for(int s=0;s<16;s++) A[s] = -expf(ld(Alog, (d<<4)+s, md));
  float wdt[4];
  #pragma unroll
  for(int j=0;j<4;j++) wdt[j] = ld(dtw, (d<<2)+j, md);
  float bdt = ld(dtb, d, md);
  float Dd = ld(Dw, d, md);
  size_t hb = ((size_t)(bm*128 + c)*128 + d) << 4;
  float h[16];
  #pragma unroll
  for(int s=0;s<16;s++) h[s] = CP[hb+s];
  __syncthreads();
  for(int tt=0;tt<32;tt++){
    float4 dt4 = *(const float4*)&sdt[tt*4];
    float v = fmaf(dt4.x,wdt[0], fmaf(dt4.y,wdt[1], fmaf(dt4.z,wdt[2], fmaf(dt4.w,wdt[3], bdt))));
    float dv = fmaxf(v,0.f) + __logf(1.f + __expf(-fabsf(v)));
    float u = bf2f(upre[tt]);
    float zv = bf2f(zpre[tt]);
    float du = dv*u;
    uint4 b0 = *(const uint4*)&sBC[tt*32];
    uint4 b1 = *(const uint4*)&sBC[tt*32 + 8];
    uint4 c0 = *(const uint4*)&sBC[tt*32 + 16];
    uint4 c1 = *(const uint4*)&sBC[tt*32 + 24];
    const bf16* B8a = (const bf16*)&b0; const bf16* B8b = (const bf16*)&b1;
    const bf16* C8a = (const bf16*)&c0; const bf16* C8b = (const bf16*)&c1;
    float y = 0.f;
    #pragma unroll
    for(int s=0;s<8;s++){
      h[s] = fmaf(h[s], __expf(dv*A[s]), du*bf2f(B8a[s]));
      y = fmaf(h[s], bf2f(C8a[s]), y);
    }
    #pragma unroll
    for(int s=0;s<8;s++){
      h[s+8] = fmaf(h[s+8], __expf(dv*A[s+8]), du*bf2f(B8b[s]));
      y = fmaf(h[s+8], bf2f(C8b[s]), y);
    }
    float yv = (y + u*Dd) * (zv / (1.f + __expf(-zv)));
    zb[(row0 + tt)*128 + d] = f2bf(yv);
  }
}

// ---------------- K6: out_proj MFMA + skip  (M=65536, K=128, N=64)
__global__ __launch_bounds__(256) void k_outproj(const bf16* __restrict__ yb, const bf16* __restrict__ xnb,
                                                 const bf16* __restrict__ wb, const void* __restrict__ ss,
                                                 bf16* __restrict__ ymb, const int* __restrict__ modep){
  __shared__ bf16 As[64*72];
  __shared__ bf16 Ws[64*72];
  const int md = *modep;
  int t = threadIdx.x;
  int bm = blockIdx.x >> 6, lt = blockIdx.x & 63;
  int p = bm >> 2, b = bm & 3, l0 = lt << 6;
  int lane = t & 63, w = t >> 6, quad = lane >> 4, lr = lane & 15;
  f4_t acc[4];
  #pragma unroll
  for(int nt=0;nt<4;nt++) acc[nt] = (f4_t){0.f,0.f,0.f,0.f};
  for(int kb=0; kb<2; kb++){
    if(kb) __syncthreads();
    int k0 = kb << 6;
    #pragma unroll
    for(int pass=0; pass<2; pass++){
      int idx = t + pass*256, r = idx >> 3, ch = idx & 7;
      *(uint4*)&As[r*72 + ch*8] = *(const uint4*)&yb[((size_t)bm*4096 + l0 + r)*128 + k0 + ch*8];
    }
    #pragma unroll
    for(int pass=0; pass<2; pass++){
      int idx = t + pass*256, o = idx >> 3, ch = idx & 7;
      *(uint4*)&Ws[o*72 + ch*8] = *(const uint4*)&wb[(size_t)o*128 + k0 + ch*8];
    }
    __syncthreads();
    #pragma unroll
    for(int kk=0; kk<64; kk+=32){
      bf8_t a = *(const bf8_t*)&As[(w*16 + lr)*72 + kk + quad*8];
      #pragma unroll
      for(int nt=0;nt<4;nt++){
        bf8_t bb = *(const bf8_t*)&Ws[(nt*16 + lr)*72 + kk + quad*8];
        acc[nt] = MFMA16(a, bb, acc[nt]);
      }
    }
  }
  __syncthreads();
  bf16* Sl = As;   // [64 l][72]
  #pragma unroll
  for(int nt=0;nt<4;nt++)
    #pragma unroll
    for(int r=0;r<4;r++)
      Sl[(w*16 + quad*4 + r)*72 + nt*16 + lr] = f2bf(acc[nt][r]);
  __syncthreads();
  float sv = ld(ss, 0, md);
  #pragma unroll
  for(int pass=0; pass<2; pass++){
    int idx = t + pass*256, l = idx >> 3, ch = idx & 7;
    size_t gi = ((size_t)b*4096 + l0 + l)*256 + p*64 + ch*8;
    uint4 yv = *(uint4*)&Sl[l*72 + ch*8];
    uint4 xv = *(const uint4*)&xnb[gi];
    const bf16* y8 = (const bf16*)&yv;
    const bf16* x8 = (const bf16*)&xv;
    uint4 ov; bf16* o8 = (bf16*)&ov;
    #pragma unroll
    for(int j=0;j<8;j++) o8[j] = f2bf(fmaf(sv, bf2f(x8[j]), bf2f(y8[j])));
    *(uint4*)&ymb[gi] = ov;
  }
}

// ---------------- K7: LayerNorm2 in-place on ym
__global__ __launch_bounds__(256) void k_ln2(bf16* __restrict__ ymb, const void* __restrict__ gam,
                                             const void* __restrict__ bet, const int* __restrict__ modep){
  const int md = *modep;
  int lane = threadIdx.x & 63, wv = threadIdx.x >> 6;
  size_t row = (size_t)blockIdx.x*4 + wv;
  bf16* rp = ymb + row*256 + (lane<<2);
  __align__(8) bf16 raw[4];
  *(ushort4*)raw = *(const ushort4*)rp;
  float v[4];
  #pragma unroll
  for(int i=0;i<4;i++) v[i] = bf2f(raw[i]);
  float s = v[0]+v[1]+v[2]+v[3];
  float s2 = v[0]*v[0]+v[1]*v[1]+v[2]*v[2]+v[3]*v[3];
  s = wred(s); s2 = wred(s2);
  float mu = s*(1.f/256.f);
  float rs = rsqrtf(s2*(1.f/256.f) - mu*mu + 1e-5f);
  int c = lane << 2;
  #pragma unroll
  for(int i=0;i<4;i++) raw[i] = f2bf((v[i]-mu)*rs*ld(gam,c+i,md) + ld(bet,c+i,md));
  *(ushort4*)rp = *(ushort4*)raw;
}

// ---------------- K8: proj MFMA (K=256, N=256) + bias, transposed store
__global__ __launch_bounds__(256) void k_proj(const bf16* __restrict__ ymb, const bf16* __restrict__ wb,
                                              const void* __restrict__ pb, bf16* __restrict__ outbb,
                                              const int* __restrict__ modep){
  __shared__ bf16 As[64*72];
  __shared__ bf16 Ws[256*72];
  const int md = *modep;
  int t = threadIdx.x;
  int row0 = blockIdx.x << 6;
  int b = row0 >> 12, l0 = row0 & 4095;
  int lane = t & 63, w = t >> 6, quad = lane >> 4, lr = lane & 15;
  f4_t acc[16];
  #pragma unroll
  for(int nt=0;nt<16;nt++) acc[nt] = (f4_t){0.f,0.f,0.f,0.f};
  for(int kb=0; kb<4; kb++){
    if(kb) __syncthreads();
    int k0 = kb << 6;
    #pragma unroll
    for(int pass=0; pass<2; pass++){
      int idx = t + pass*256, r = idx >> 3, ch = idx & 7;
      *(uint4*)&As[r*72 + ch*8] = *(const uint4*)&ymb[((size_t)(row0 + r))*256 + k0 + ch*8];
    }
    #pragma unroll
    for(int pass=0; pass<8; pass++){
      int idx = t + pass*256, e = idx >> 3, ch = idx & 7;
      *(uint4*)&Ws[e*72 + ch*8] = *(const uint4*)&wb[(size_t)e*256 + k0 + ch*8];
    }
    __syncthreads();
    #pragma unroll
    for(int kk=0; kk<64; kk+=32){
      bf8_t a = *(const bf8_t*)&As[(w*16 + lr)*72 + kk + quad*8];
      #pragma unroll
      for(int nt=0;nt<16;nt++){
        bf8_t bb = *(const bf8_t*)&Ws[(nt*16 + lr)*72 + kk + quad*8];
        acc[nt] = MFMA16(a, bb, acc[nt]);
      }
    }
  }
  __syncthreads();
  bf16* Sl = Ws;   // [256 o][72 l]
  #pragma unroll
  for(int nt=0;nt<16;nt++){
    float bv = ld(pb, nt*16 + lr, md);
    #pragma unroll
    for(int r=0;r<4;r++)
      Sl[(nt*16 + lr)*72 + w*16 + quad*4 + r] = f2bf(acc[nt][r] + bv);
  }
  __syncthreads();
  #pragma unroll
  for(int pass=0; pass<8; pass++){
    int idx = t + pass*256, o = idx >> 3, ch = idx & 7;
    uint4 v = *(uint4*)&Sl[o*72 + ch*8];
    *(uint4*)&outbb[((size_t)(b*256 + o) << 12) + l0 + ch*8] = v;
  }
}

// ---------------- K9a: theta, coalesced: block = 64 hw x 4 c-segments
__global__ __launch_bounds__(256) void k_theta(const bf16* __restrict__ outbb, const void* __restrict__ tw,
                                               const void* __restrict__ tb, float* __restrict__ theta,
                                               const int* __restrict__ modep){
  __shared__ float red[4][64];
  const int md = *modep;
  int t = threadIdx.x;
  int lane = t & 63, w = t >> 6;
  int b = blockIdx.x >> 6;
  int hw0 = (blockIdx.x & 63) << 6;
  const bf16* base = outbb + ((size_t)b << 20) + hw0 + lane;
  float a0=0.f, a1=0.f, a2=0.f, a3=0.f;
  #pragma unroll 4
  for(int cc=0; cc<64; cc+=4){
    int c = (w<<6) + cc;
    a0 = fmaf(bf2f(base[(size_t)(c+0) << 12]), ld(tw, c+0, md), a0);
    a1 = fmaf(bf2f(base[(size_t)(c+1) << 12]), ld(tw, c+1, md), a1);
    a2 = fmaf(bf2f(base[(size_t)(c+2) << 12]), ld(tw, c+2, md), a2);
    a3 = fmaf(bf2f(base[(size_t)(c+3) << 12]), ld(tw, c+3, md), a3);
  }
  red[w][lane] = (a0+a1) + (a2+a3);
  __syncthreads();
  if(w == 0){
    float v = red[0][lane] + red[1][lane] + red[2][lane] + red[3][lane] + ld(tb, 0, md);
    theta[((size_t)b << 12) + hw0 + lane] = 1.f / (1.f + __expf(-v));
  }
}

// ---------------- K9b: depthwise 3x3 + CDC + exact GELU -> gbuf (bf16)
__global__ __launch_bounds__(256) void k_cdc(const bf16* __restrict__ outbb, const float* __restrict__ theta,
                                             const void* __restrict__ cw, bf16* __restrict__ gbufb,
                                             const int* __restrict__ modep){
  const int md = *modep;
  int g = blockIdx.x*256 + threadIdx.x;
  int hw = g & 4095;
  int c = (g >> 12) & 255;
  int b = g >> 20;
  int w0 = hw & 63, h0 = hw >> 6;
  float wk[9]; float ks = 0.f;
  #pragma unroll
  for(int j=0;j<9;j++){ wk[j] = ld(cw, c*9 + j, md); ks += wk[j]; }
  const bf16* base = outbb + (((size_t)b*256 + c) << 12);
  float on = 0.f;
  #pragma unroll
  for(int dy=-1;dy<=1;dy++){
    #pragma unroll
    for(int dx=-1;dx<=1;dx++){
      int hh = h0+dy, ww = w0+dx;
      if(hh>=0 && hh<64 && ww>=0 && ww<64)
        on = fmaf(bf2f(base[(hh<<6)+ww]), wk[(dy+1)*3 + dx+1], on);
    }
  }
  float ctr  = bf2f(base[hw]);
  float edge = on - ctr*ks;
  float th   = theta[((size_t)b<<12) + hw];
  float cd   = fmaf(th, edge, on);
  gbufb[g] = f2bf(0.5f * cd * (1.f + erff(cd * 0.70710678118654752f)));
}

// ---------------- K10: 1x1 pw MFMA + residual, dual-dtype store
__global__ __launch_bounds__(256) void k_pw(const bf16* __restrict__ gbufb, const bf16* __restrict__ outbb,
                                            const bf16* __restrict__ wb, void* __restrict__ outp,
                                            const int* __restrict__ modep){
  __shared__ bf16 As[64*72];
  __shared__ bf16 Bs[256*72];
  const int md = *modep;
  int t = threadIdx.x;
  int b  = blockIdx.x >> 6;
  int ot = (blockIdx.x >> 4) & 3;
  int ht = blockIdx.x & 15;
  int o0 = ot << 6, hw0 = ht << 8;
  int lane = t & 63, w = t >> 6, quad = lane >> 4, lr = lane & 15;
  f4_t acc[16];
  #pragma unroll
  for(int nt=0;nt<16;nt++) acc[nt] = (f4_t){0.f,0.f,0.f,0.f};
  for(int kb=0; kb<4; kb++){
    if(kb) __syncthreads();
    int k0 = kb << 6;
    #pragma unroll
    for(int pass=0; pass<2; pass++){
      int idx = t + pass*256, r = idx >> 3, ch = idx & 7;
      *(uint4*)&As[r*72 + ch*8] = *(const uint4*)&wb[(size_t)(o0 + r)*256 + k0 + ch*8];
    }
    #pragma unroll
    for(int pass=0; pass<8; pass++){
      int idx = t + pass*256, cc = idx >> 5, hc = idx & 31;
      uint4 gv = *(const uint4*)&gbufb[((size_t)(b*256 + k0 + cc) << 12) + hw0 + hc*8];
      const bf16* g8 = (const bf16*)&gv;
      #pragma unroll
      for(int j=0;j<8;j++) Bs[(hc*8 + j)*72 + cc] = g8[j];
    }
    __syncthreads();
    #pragma unroll
    for(int kk=0; kk<64; kk+=32){
      bf8_t a = *(const bf8_t*)&As[(w*16 + lr)*72 + kk + quad*8];
      #pragma unroll
      for(int nt=0;nt<16;nt++){
        bf8_t bb = *(const bf8_t*)&Bs[(nt*16 + lr)*72 + kk + quad*8];
        acc[nt] = MFMA16(a, bb, acc[nt]);
      }
    }
  }
  __syncthreads();
  bf16* Sl = Bs;  // [64 o][264 hw]
  #pragma unroll
  for(int nt=0;nt<16;nt++)
    #pragma unroll
    for(int r=0;r<4;r++)
      Sl[(w*16 + quad*4 + r)*264 + nt*16 + lr] = f2bf(acc[nt][r]);
  __syncthreads();
  #pragma unroll
  for(int pass=0; pass<8; pass++){
    int idx = t + pass*256, ol = idx >> 5, c16 = idx & 31;
    size_t ro = ((size_t)(b*256 + o0 + ol) << 12) + hw0 + c16*8;
    uint4 sv = *(uint4*)&Sl[ol*264 + c16*8];
    uint4 rv = *(const uint4*)&outbb[ro];
    const bf16* s8 = (const bf16*)&sv;
    const bf16* r8 = (const bf16*)&rv;
    if(md){
      float4 f0, f1;
      f0.x = bf2f(s8[0]) + bf2f(r8[0]); f0.y = bf2f(s8[1]) + bf2f(r8[1]);
      f0.z = bf2f(s8[2]) + bf2f(r8[2]); f0.w = bf2f(s8[3]) + bf2f(r8[3]);
      f1.x = bf2f(s8[4]) + bf2f(r8[4]); f1.y = bf2f(s8[5]) + bf2f(r8[5]);
      f1.z = bf2f(s8[6]) + bf2f(r8[6]); f1.w = bf2f(s8[7]) + bf2f(r8[7]);
      *(float4*)&((float*)outp)[ro]     = f0;
      *(float4*)&((float*)outp)[ro + 4] = f1;
    } else {
      uint4 ov; bf16* o8 = (bf16*)&ov;
      #pragma unroll
      for(int j=0;j<8;j++) o8[j] = f2bf(bf2f(s8[j]) + bf2f(r8[j]));
      *(uint4*)&((bf16*)outp)[ro] = ov;
    }
  }
}

extern "C" void kernel_launch(void* const* d_in, const int* in_sizes, int n_in,
                              void* d_out, int out_size, void* d_ws, size_t ws_size,
                              hipStream_t stream){
  const void* x      = d_in[0];
  const void* ln_g   = d_in[1];
  const void* ln_b   = d_in[2];
  const void* inw    = d_in[3];
  const void* convw  = d_in[4];
  const void* convb  = d_in[5];
  const void* xpw    = d_in[6];
  const void* dtw    = d_in[7];
  const void* dtb    = d_in[8];
  const void* Alog   = d_in[9];
  const void* Dw     = d_in[10];
  const void* outw   = d_in[11];
  const void* sscale = d_in[12];
  const void* projw  = d_in[13];
  const void* projb  = d_in[14];
  const void* cdcw   = d_in[15];
  const void* thw    = d_in[16];
  const void* thb    = d_in[17];
  const void* pww    = d_in[18];
  float* ws = (float*)d_ws;

  // ---- Workspace layout (f32 slots) ----
  // [0, 2097152)          xnb  bf16 [4][4096][256]
  // [2097152, 6291456)    xcb bf16 | CP f32 [16][128][2048] | ymb/outbb aliases
  // [6291456, 10485760)   zb  bf16 [16][4096][128] | gbufb alias
  // [10485760, 14680064)  xsb bf16 | theta alias
  // [14680064, 14942208)  xdt f32 [65536][4]
  // [14942208, 15990784)  xbc bf16 [65536][32]
  // [17039360]            flag ; [17039364,...) bf16 weights
  bf16*  xnb   = (bf16*)(ws);
  bf16*  xcb   = (bf16*)(ws + 2097152);
  float* CP    = ws + 2097152;
  bf16*  ymb   = (bf16*)(ws + 2097152);
  bf16*  outbb = (bf16*)(ws + 4194304);
  bf16*  zb    = (bf16*)(ws + 6291456);
  bf16*  gbufb = (bf16*)(ws + 6291456);
  bf16*  xsb   = (bf16*)(ws + 10485760);
  float* theta = ws + 10485760;
  float* xdt   = ws + 14680064;
  bf16*  xbc   = (bf16*)(ws + 14942208);
  int*   flag  = (int*)(ws + 17039360);
  bf16*  wsb   = (bf16*)(ws + 17039364);
  bf16*  inwb  = wsb;
  bf16*  outwb = wsb + 16384;
  bf16*  projwb= wsb + 24576;
  bf16*  pwwb  = wsb + 90112;
  bf16*  CSb   = (bf16*)d_out;   // dead scratch until k_pw writes it

  k_detect <<<1,    256, 0, stream>>>((const unsigned short*)x, flag);
  k_wcvt   <<<608,  256, 0, stream>>>(inw, outw, projw, pww, wsb, flag);
  k_ln1    <<<4096, 256, 0, stream>>>(x, ln_g, ln_b, xnb, flag);
  k_inproj <<<1024, 256, 0, stream>>>(xnb, inwb, xcb, zb);
  k_conv   <<<8192, 256, 0, stream>>>(xcb, convw, convb, xsb, flag);
  k_xproj  <<<1024, 256, 0, stream>>>(xsb, xpw, xdt, xbc, flag);
  k_scan1  <<<2048, 128, 0, stream>>>(xsb, xdt, xbc, dtw, dtb, Alog, CP, CSb, flag);
  k_scan2  <<<128,  256, 0, stream>>>(CP, CSb);
  k_scan3  <<<2048, 128, 0, stream>>>(zb, xsb, xdt, xbc, dtw, dtb, Alog, Dw, CP, flag);
  k_outproj<<<1024, 256, 0, stream>>>(zb, xnb, outwb, sscale, ymb, flag);
  k_ln2    <<<4096, 256, 0, stream>>>(ymb, ln_g, ln_b, flag);
  k_proj   <<<256,  256, 0, stream>>>(ymb, projwb, projb, outbb, flag);
  k_theta  <<<256,  256, 0, stream>>>(outbb, thw, thb, theta, flag);
  k_cdc    <<<16384,256, 0, stream>>>(outbb, theta, cdcw, gbufb, flag);
  k_pw     <<<256,  256, 0, stream>>>(gbufb, outbb, pwwb, d_out, flag);
}